// Round 10
// baseline (40.908 us; speedup 1.0000x reference)
//
#include <hip/hip_runtime.h>
#include <hip/hip_bf16.h>

#define NN 2048
#define KD 512
#define ODIM 512
#define NHEAD 8
#define HD 64
#define NEG 0.2f

typedef float f32x4 __attribute__((ext_vector_type(4)));
typedef short bf16x8 __attribute__((ext_vector_type(8)));
typedef short bf16x4 __attribute__((ext_vector_type(4)));
typedef unsigned long long u64;
typedef unsigned int u32;

__device__ __forceinline__ short tob(float f) {
  __hip_bfloat16 h = __float2bfloat16(f);
  return *reinterpret_cast<short*>(&h);
}

// async global -> LDS; LDS dest = uniform base + lane*width
__device__ __forceinline__ void gl_lds16(const void* g, void* l) {
  __builtin_amdgcn_global_load_lds(
      (const __attribute__((address_space(1))) u32*)g,
      (__attribute__((address_space(3))) u32*)l, 16, 0, 0);
}

// ---------------------------------------------------------------------------
// prep: blocks 0..1023   pack adj -> bitmask
//       blocks 1024..1151 Xf: X (f32) -> bf16 in MFMA-A-fragment order
//       blocks 1152..1215 Bf: W (f32) -> bf16 in MFMA-B-fragment order
// ---------------------------------------------------------------------------
__global__ __launch_bounds__(256) void prep(const float* __restrict__ X,
                                            const float* __restrict__ W,
                                            const int* __restrict__ adj,
                                            short* __restrict__ Xf,
                                            short* __restrict__ Bf,
                                            unsigned short* __restrict__ bits) {
  __shared__ float sbuf[16 * 516];
  const int b = blockIdx.x;
  const int t = threadIdx.x;

  if (b < 1024) {  // ---- adj pack ----
    const int T = b * 256 + t;
    const int row = T >> 7, g = T & 127;
    const int* p = adj + (size_t)row * NN + g * 16;
    u32 m = 0;
#pragma unroll
    for (int q = 0; q < 4; ++q) {
      const int4 v = *(const int4*)&p[q * 4];
      m |= (v.x > 0 ? 1u : 0u) << (q * 4);
      m |= (v.y > 0 ? 2u : 0u) << (q * 4);
      m |= (v.z > 0 ? 4u : 0u) << (q * 4);
      m |= (v.w > 0 ? 8u : 0u) << (q * 4);
    }
    bits[T] = (unsigned short)m;
    return;
  }

  if (b < 1024 + 128) {  // ---- X -> Xf ----
    const int xb = b - 1024;
#pragma unroll
    for (int q = 0; q < 8; ++q) {
      const int flat = q * 256 + t;
      const int row = flat >> 7, c4 = flat & 127;
      const float4 v = *(const float4*)&X[(size_t)(xb * 16 + row) * KD + c4 * 4];
      *(float4*)&sbuf[row * 516 + c4 * 4] = v;
    }
    __syncthreads();
#pragma unroll
    for (int c = 0; c < 4; ++c) {
      const int s = c * 256 + t;
      const int l = s & 63;
      const int col = l & 15, kg = (l >> 4) & 3;
      const int k0 = (s >> 6) * 32 + kg * 8;
      bf16x8 o;
#pragma unroll
      for (int u = 0; u < 8; ++u) o[u] = tob(sbuf[col * 516 + k0 + u]);
      *(bf16x8*)&Xf[((size_t)xb * 1024 + s) * 8] = o;
    }
    return;
  }

  // ---- W -> Bf ----
  const int b2 = b - 1152;
  const int kb = b2 & 7, h = b2 >> 3;
  const int k0 = kb * 64;
#pragma unroll
  for (int q = 0; q < 4; ++q) {
    const int flat = q * 256 + t;
    const int kk = flat >> 4, o4 = (flat & 15) * 4;
    const float4 v = *(const float4*)&W[(size_t)(k0 + kk) * ODIM + h * 64 + o4];
    *(float4*)&sbuf[kk * 68 + o4] = v;
  }
  __syncthreads();
#pragma unroll
  for (int c = 0; c < 2; ++c) {
    const int s = c * 256 + t;
    const int ksl = s >> 8, nt = (s >> 6) & 3, l = s & 63;
    const int col = l & 15, kg = (l >> 4) & 3;
    const int kloc = ksl * 32 + kg * 8;
    const int od = nt * 16 + col;
    bf16x8 o;
#pragma unroll
    for (int u = 0; u < 8; ++u) o[u] = tob(sbuf[(kloc + u) * 68 + od]);
    const size_t off = (((size_t)(h * 4 + nt) * 16 + kb * 2 + ksl) * 64 + l) * 8;
    *(bf16x8*)&Bf[off] = o;
  }
}

// ---------------------------------------------------------------------------
// gemm_fused: Wh = x @ W via MFMA from fragment-ordered Xf/Bf. No LDS, no
// barriers. Epilogue: fragment-ordered WhF + exp tables.
// ---------------------------------------------------------------------------
__global__ __launch_bounds__(256) void gemm_fused(
    const short* __restrict__ Xf, const short* __restrict__ Bf,
    const float* __restrict__ a, short* __restrict__ WhF,
    float2* __restrict__ esrcp, u32* __restrict__ edstp) {
  const int t = threadIdx.x;
  const int lane = t & 63, w = t >> 6;
  const int col = lane & 15, kgrp = lane >> 4;
  const int bm = blockIdx.x * 64;
  const int h = blockIdx.y;
  const int mt = blockIdx.x * 4 + w;

  const short* ax = Xf + (size_t)mt * 8192;
  const short* bx = Bf + (size_t)h * 32768;

  f32x4 acc[4] = {};

#pragma unroll
  for (int ks = 0; ks < 16; ++ks) {
    const bf16x8 af = *(const bf16x8*)&ax[(ks * 64 + lane) * 8];
#pragma unroll
    for (int nt = 0; nt < 4; ++nt) {
      const bf16x8 bf = *(const bf16x8*)&bx[((nt * 16 + ks) * 64 + lane) * 8];
      acc[nt] = __builtin_amdgcn_mfma_f32_16x16x32_bf16(af, bf, acc[nt], 0, 0, 0);
    }
  }

  float asv[4], adv[4];
#pragma unroll
  for (int nt = 0; nt < 4; ++nt) {
    asv[nt] = a[nt * 16 + col];
    adv[nt] = a[64 + nt * 16 + col];
  }
  float ps[4], pd[4];
#pragma unroll
  for (int r = 0; r < 4; ++r) {
    float s1 = 0.f, s2 = 0.f;
#pragma unroll
    for (int nt = 0; nt < 4; ++nt) {
      s1 += acc[nt][r] * asv[nt];
      s2 += acc[nt][r] * adv[nt];
    }
    ps[r] = s1;
    pd[r] = s2;
  }
#pragma unroll
  for (int off = 1; off <= 8; off <<= 1) {
#pragma unroll
    for (int r = 0; r < 4; ++r) {
      ps[r] += __shfl_xor(ps[r], off);
      pd[r] += __shfl_xor(pd[r], off);
    }
  }
  {
    const size_t tbase = ((size_t)h * 32 + blockIdx.x) * 4096;
    const int lp = ((w & 1) * 2 + (kgrp >> 1)) * 16 + col;
    const int u0 = (kgrp & 1) * 4;
    const int slot_ks = w >> 1;
#pragma unroll
    for (int nt = 0; nt < 4; ++nt) {
      bf16x4 o;
#pragma unroll
      for (int r = 0; r < 4; ++r) o[r] = tob(acc[nt][r]);
      *(bf16x4*)&WhF[tbase + (size_t)(nt * 2 + slot_ks) * 512 + lp * 8 + u0] = o;
    }
  }
  if (col == 0) {
    const int mbase = bm + w * 16 + kgrp * 4;
#pragma unroll
    for (int r = 0; r < 4; ++r) {
      const int n = mbase + r;
      esrcp[h * NN + n] = make_float2(__expf(ps[r]), __expf(NEG * ps[r]));
      const u32 lo = (u32)(unsigned short)tob(__expf(pd[r]));
      const u32 hi = (u32)(unsigned short)tob(__expf(NEG * pd[r]));
      edstp[h * NN + n] = (hi << 16) | lo;
    }
  }
}

// ---------------------------------------------------------------------------
// attn_partial: grid (16 ichunk, 8 h, 4 jq), 512 thr = 8 waves.
// Block covers 128 i-rows x 512 j for one head. Prologue: stage 64 KB of
// fragment-ordered WhF (64 DMAs) + 2 KB edstp into LDS; per-wave register
// loads of adj words + esrcp. ONE barrier. Main loop (wave = one 16-row
// i-tile): 8 j-tiles x {8 ds_read_b128 + p-gen + 10 MFMA} — zero global
// memory dependencies. Partials (num + den) stored f32 to ws; cross-jq
// reduction is a separate kernel.
// ---------------------------------------------------------------------------
__global__ __launch_bounds__(512, 4) void attn_partial(
    const short* __restrict__ WhF, const unsigned char* __restrict__ adjbits,
    const float2* __restrict__ esrcp, const u32* __restrict__ edstp,
    float* __restrict__ Pnum, float* __restrict__ Pden) {
  extern __shared__ __align__(16) char smem[];  // 64KB B-frags + 2KB edstp
  const int t = threadIdx.x;
  const int lane = t & 63;
  const int wid = t >> 6;  // = i-tile within chunk
  const int col = lane & 15, kgrp = lane >> 4;
  const int ic = blockIdx.x;
  const int h = blockIdx.y;
  const int jq = blockIdx.z;
  const int i0w = ic * 128 + wid * 16;

  // ---- prologue: stage this block's working set ----
  {
    // B-fragments: wave wid stages j-tile jt=wid (8 slots x 1KB)
    const short* g = WhF + ((size_t)(h * 32 + jq * 8 + wid)) * 4096;
#pragma unroll
    for (int s = 0; s < 8; ++s)
      gl_lds16(g + s * 512 + lane * 8, smem + (wid * 8 + s) * 1024);
    // edstp tile (512 u32 = 2KB): wave 0 stages it
    if (wid == 0) {
#pragma unroll
      for (int d = 0; d < 2; ++d)
        gl_lds16(edstp + h * NN + jq * 512 + d * 256 + lane * 4,
                 smem + 65536 + d * 1024);
    }
  }
  // adj words for this wave's 16 rows x 512 j: 4 uint4 per lane
  u64 aw[8];
  {
    const unsigned char* rb =
        adjbits + (size_t)(i0w + col) * (NN / 8) + jq * 64;
#pragma unroll
    for (int q = 0; q < 4; ++q) {
      const uint4 v = *(const uint4*)(rb + q * 16);
      aw[q * 2] = (u64)v.x | ((u64)v.y << 32);
      aw[q * 2 + 1] = (u64)v.z | ((u64)v.w << 32);
    }
  }
  const float2 e0 = esrcp[h * NN + i0w + col];
  const float A0 = e0.x, C0 = e0.y;

  bf16x8 ones;
#pragma unroll
  for (int u = 0; u < 8; ++u) ones[u] = (short)0x3F80;

  __syncthreads();  // staging complete (compiler drains vmcnt before barrier)

  f32x4 acc[4] = {};
  f32x4 accd = {};
  const u32* elds = (const u32*)(smem + 65536);

#pragma unroll
  for (int jt = 0; jt < 8; ++jt) {
    const short* sb = (const short*)(smem + jt * 8192);
    // p-gen for this (i-tile, j-tile): 16 p per lane
    bf16x8 af[2];
#pragma unroll
    for (int ks = 0; ks < 2; ++ks) {
      const uint4 q0 = *(const uint4*)&elds[jt * 64 + ks * 32 + kgrp * 8];
      const uint4 q1 = *(const uint4*)&elds[jt * 64 + ks * 32 + kgrp * 8 + 4];
      const u32 mb = (u32)(aw[jt] >> ((ks * 4 + kgrp) * 8)) & 0xffu;
      const u32 uw[8] = {q0.x, q0.y, q0.z, q0.w, q1.x, q1.y, q1.z, q1.w};
#pragma unroll
      for (int u2 = 0; u2 < 8; ++u2) {
        const float B = __uint_as_float(uw[u2] << 16);
        const float D = __uint_as_float(uw[u2] & 0xffff0000u);
        float p = fmaxf(A0 * B, C0 * D);
        p = ((mb >> u2) & 1u) ? p : 0.f;
        af[ks][u2] = tob(p);
      }
    }
    // MFMAs: 2 den + 8 od (B from LDS, resident)
    accd = __builtin_amdgcn_mfma_f32_16x16x32_bf16(af[0], ones, accd, 0, 0, 0);
    accd = __builtin_amdgcn_mfma_f32_16x16x32_bf16(af[1], ones, accd, 0, 0, 0);
#pragma unroll
    for (int nt = 0; nt < 4; ++nt) {
      const bf16x8 b0 = *(const bf16x8*)&sb[(nt * 2 + 0) * 512 + lane * 8];
      const bf16x8 b1 = *(const bf16x8*)&sb[(nt * 2 + 1) * 512 + lane * 8];
      acc[nt] = __builtin_amdgcn_mfma_f32_16x16x32_bf16(af[0], b0, acc[nt], 0, 0, 0);
      acc[nt] = __builtin_amdgcn_mfma_f32_16x16x32_bf16(af[1], b1, acc[nt], 0, 0, 0);
    }
  }

  // ---- store partials (fragment order, fully coalesced) ----
  const int itg = ic * 8 + wid;
  const size_t pb = (((size_t)(jq * 8 + h) * 128 + itg) * 4) * 256;
#pragma unroll
  for (int nt = 0; nt < 4; ++nt)
    *(f32x4*)&Pnum[pb + (size_t)nt * 256 + lane * 4] = acc[nt];
  if (col == 0) {
    *(f32x4*)&Pden[(((size_t)(jq * 8 + h) * 128 + itg) * 16) + kgrp * 4] = accd;
  }
}

// ---------------------------------------------------------------------------
// reduce: sum 4 jq partials, divide by summed denominator, write out.
// grid 1024 = (h 8) x (itile 128); 256 thr.
// ---------------------------------------------------------------------------
__global__ __launch_bounds__(256) void reduce(const float* __restrict__ Pnum,
                                              const float* __restrict__ Pden,
                                              float* __restrict__ out) {
  __shared__ float lds[16][68];
  const int t = threadIdx.x;
  const int it = blockIdx.x & 127, h = blockIdx.x >> 7;
  const int nt = t >> 6, l = t & 63;
  const int col = l & 15, kgrp = l >> 4;

  f32x4 s = {};
  f32x4 dd = {};
#pragma unroll
  for (int jq = 0; jq < 4; ++jq) {
    const size_t pb = (((size_t)(jq * 8 + h) * 128 + it) * 4) * 256;
    const f32x4 v = *(const f32x4*)&Pnum[pb + (size_t)nt * 256 + l * 4];
    const f32x4 d =
        *(const f32x4*)&Pden[(((size_t)(jq * 8 + h) * 128 + it) * 16) + kgrp * 4];
#pragma unroll
    for (int r = 0; r < 4; ++r) {
      s[r] += v[r];
      dd[r] += d[r];
    }
  }
#pragma unroll
  for (int r = 0; r < 4; ++r) lds[kgrp * 4 + r][nt * 16 + col] = s[r] / dd[r];
  __syncthreads();

  const int row = t >> 4, q = t & 15;
  const float4 o = *(const float4*)&lds[row][q * 4];
  out[(size_t)(it * 16 + row) * ODIM + h * HD + q * 4] = o.x;
  *(float4*)&out[(size_t)(it * 16 + row) * ODIM + h * HD + q * 4] = o;
}

// ---------------------------------------------------------------------------
extern "C" void kernel_launch(void* const* d_in, const int* in_sizes, int n_in,
                              void* d_out, int out_size, void* d_ws,
                              size_t ws_size, hipStream_t stream) {
  const float* x = (const float*)d_in[0];
  const int* adj = (const int*)d_in[1];
  const float* W = (const float*)d_in[2];
  const float* a = (const float*)d_in[3];
  float* out = (float*)d_out;

  char* ws = (char*)d_ws;
  short* WhF = (short*)ws;                                    // 2 MB
  short* Xf = (short*)(ws + (2 << 20));                       // 2 MB
  short* Bf = (short*)(ws + (4 << 20));                       // 512 KB
  unsigned short* bits =
      (unsigned short*)(ws + (4 << 20) + (512 << 10));        // 512 KB
  float2* esrcp = (float2*)(ws + (5 << 20));                  // 128 KB
  u32* edstp = (u32*)(ws + (5 << 20) + (128 << 10));          // 64 KB
  float* Pnum = (float*)(ws + (6 << 20));                     // 16.8 MB
  float* Pden = (float*)(ws + (23 << 20));                    // 256 KB

  prep<<<1216, 256, 0, stream>>>(x, W, adj, Xf, Bf, bits);
  gemm_fused<<<dim3(32, 8), 256, 0, stream>>>(Xf, Bf, a, WhF, esrcp, edstp);
  attn_partial<<<dim3(16, 8, 4), 512, 67584, stream>>>(
      WhF, (const unsigned char*)bits, esrcp, edstp, Pnum, Pden);
  reduce<<<1024, 256, 0, stream>>>(Pnum, Pden, out);
}

// Round 11
// 36.566 us; speedup vs baseline: 1.1188x; 1.1188x over previous
//
#include <hip/hip_runtime.h>
#include <hip/hip_bf16.h>

#define NN 2048
#define KD 512
#define ODIM 512
#define NHEAD 8
#define HD 64
#define NEG 0.2f

typedef float f32x4 __attribute__((ext_vector_type(4)));
typedef short bf16x8 __attribute__((ext_vector_type(8)));
typedef short bf16x4 __attribute__((ext_vector_type(4)));
typedef unsigned long long u64;
typedef unsigned int u32;

__device__ __forceinline__ short tob(float f) {
  __hip_bfloat16 h = __float2bfloat16(f);
  return *reinterpret_cast<short*>(&h);
}

// async global -> LDS; LDS dest = uniform base + lane*width
__device__ __forceinline__ void gl_lds16(const void* g, void* l) {
  __builtin_amdgcn_global_load_lds(
      (const __attribute__((address_space(1))) u32*)g,
      (__attribute__((address_space(3))) u32*)l, 16, 0, 0);
}

// ---------------------------------------------------------------------------
// prep: blocks 0..1023   pack adj -> bitmask
//       blocks 1024..1151 Xf: X (f32) -> bf16 in MFMA-A-fragment order
//       blocks 1152..1215 Bf: W (f32) -> bf16 in MFMA-B-fragment order
// ---------------------------------------------------------------------------
__global__ __launch_bounds__(256) void prep(const float* __restrict__ X,
                                            const float* __restrict__ W,
                                            const int* __restrict__ adj,
                                            short* __restrict__ Xf,
                                            short* __restrict__ Bf,
                                            unsigned short* __restrict__ bits) {
  __shared__ float sbuf[16 * 516];
  const int b = blockIdx.x;
  const int t = threadIdx.x;

  if (b < 1024) {  // ---- adj pack ----
    const int T = b * 256 + t;
    const int row = T >> 7, g = T & 127;
    const int* p = adj + (size_t)row * NN + g * 16;
    u32 m = 0;
#pragma unroll
    for (int q = 0; q < 4; ++q) {
      const int4 v = *(const int4*)&p[q * 4];
      m |= (v.x > 0 ? 1u : 0u) << (q * 4);
      m |= (v.y > 0 ? 2u : 0u) << (q * 4);
      m |= (v.z > 0 ? 4u : 0u) << (q * 4);
      m |= (v.w > 0 ? 8u : 0u) << (q * 4);
    }
    bits[T] = (unsigned short)m;
    return;
  }

  if (b < 1024 + 128) {  // ---- X -> Xf ----
    const int xb = b - 1024;
#pragma unroll
    for (int q = 0; q < 8; ++q) {
      const int flat = q * 256 + t;
      const int row = flat >> 7, c4 = flat & 127;
      const float4 v = *(const float4*)&X[(size_t)(xb * 16 + row) * KD + c4 * 4];
      *(float4*)&sbuf[row * 516 + c4 * 4] = v;
    }
    __syncthreads();
#pragma unroll
    for (int c = 0; c < 4; ++c) {
      const int s = c * 256 + t;
      const int l = s & 63;
      const int col = l & 15, kg = (l >> 4) & 3;
      const int k0 = (s >> 6) * 32 + kg * 8;
      bf16x8 o;
#pragma unroll
      for (int u = 0; u < 8; ++u) o[u] = tob(sbuf[col * 516 + k0 + u]);
      *(bf16x8*)&Xf[((size_t)xb * 1024 + s) * 8] = o;
    }
    return;
  }

  // ---- W -> Bf ----
  const int b2 = b - 1152;
  const int kb = b2 & 7, h = b2 >> 3;
  const int k0 = kb * 64;
#pragma unroll
  for (int q = 0; q < 4; ++q) {
    const int flat = q * 256 + t;
    const int kk = flat >> 4, o4 = (flat & 15) * 4;
    const float4 v = *(const float4*)&W[(size_t)(k0 + kk) * ODIM + h * 64 + o4];
    *(float4*)&sbuf[kk * 68 + o4] = v;
  }
  __syncthreads();
#pragma unroll
  for (int c = 0; c < 2; ++c) {
    const int s = c * 256 + t;
    const int ksl = s >> 8, nt = (s >> 6) & 3, l = s & 63;
    const int col = l & 15, kg = (l >> 4) & 3;
    const int kloc = ksl * 32 + kg * 8;
    const int od = nt * 16 + col;
    bf16x8 o;
#pragma unroll
    for (int u = 0; u < 8; ++u) o[u] = tob(sbuf[(kloc + u) * 68 + od]);
    const size_t off = (((size_t)(h * 4 + nt) * 16 + kb * 2 + ksl) * 64 + l) * 8;
    *(bf16x8*)&Bf[off] = o;
  }
}

// ---------------------------------------------------------------------------
// gemm_fused: Wh = x @ W via MFMA from fragment-ordered Xf/Bf. No LDS, no
// barriers. Epilogue: fragment-ordered WhF + exp tables.
// ---------------------------------------------------------------------------
__global__ __launch_bounds__(256) void gemm_fused(
    const short* __restrict__ Xf, const short* __restrict__ Bf,
    const float* __restrict__ a, short* __restrict__ WhF,
    float2* __restrict__ esrcp, u32* __restrict__ edstp) {
  const int t = threadIdx.x;
  const int lane = t & 63, w = t >> 6;
  const int col = lane & 15, kgrp = lane >> 4;
  const int bm = blockIdx.x * 64;
  const int h = blockIdx.y;
  const int mt = blockIdx.x * 4 + w;

  const short* ax = Xf + (size_t)mt * 8192;
  const short* bx = Bf + (size_t)h * 32768;

  f32x4 acc[4] = {};

#pragma unroll
  for (int ks = 0; ks < 16; ++ks) {
    const bf16x8 af = *(const bf16x8*)&ax[(ks * 64 + lane) * 8];
#pragma unroll
    for (int nt = 0; nt < 4; ++nt) {
      const bf16x8 bf = *(const bf16x8*)&bx[((nt * 16 + ks) * 64 + lane) * 8];
      acc[nt] = __builtin_amdgcn_mfma_f32_16x16x32_bf16(af, bf, acc[nt], 0, 0, 0);
    }
  }

  float asv[4], adv[4];
#pragma unroll
  for (int nt = 0; nt < 4; ++nt) {
    asv[nt] = a[nt * 16 + col];
    adv[nt] = a[64 + nt * 16 + col];
  }
  float ps[4], pd[4];
#pragma unroll
  for (int r = 0; r < 4; ++r) {
    float s1 = 0.f, s2 = 0.f;
#pragma unroll
    for (int nt = 0; nt < 4; ++nt) {
      s1 += acc[nt][r] * asv[nt];
      s2 += acc[nt][r] * adv[nt];
    }
    ps[r] = s1;
    pd[r] = s2;
  }
#pragma unroll
  for (int off = 1; off <= 8; off <<= 1) {
#pragma unroll
    for (int r = 0; r < 4; ++r) {
      ps[r] += __shfl_xor(ps[r], off);
      pd[r] += __shfl_xor(pd[r], off);
    }
  }
  {
    const size_t tbase = ((size_t)h * 32 + blockIdx.x) * 4096;
    const int lp = ((w & 1) * 2 + (kgrp >> 1)) * 16 + col;
    const int u0 = (kgrp & 1) * 4;
    const int slot_ks = w >> 1;
#pragma unroll
    for (int nt = 0; nt < 4; ++nt) {
      bf16x4 o;
#pragma unroll
      for (int r = 0; r < 4; ++r) o[r] = tob(acc[nt][r]);
      *(bf16x4*)&WhF[tbase + (size_t)(nt * 2 + slot_ks) * 512 + lp * 8 + u0] = o;
    }
  }
  if (col == 0) {
    const int mbase = bm + w * 16 + kgrp * 4;
#pragma unroll
    for (int r = 0; r < 4; ++r) {
      const int n = mbase + r;
      esrcp[h * NN + n] = make_float2(__expf(ps[r]), __expf(NEG * ps[r]));
      const u32 lo = (u32)(unsigned short)tob(__expf(pd[r]));
      const u32 hi = (u32)(unsigned short)tob(__expf(NEG * pd[r]));
      edstp[h * NN + n] = (hi << 16) | lo;
    }
  }
}

// ---------------------------------------------------------------------------
// attn_mfma: grid (64, 8), 256 thr = 4 waves = 4 j-quarters over 32 i-rows.
// Per-wave LDS: [2 x 8KB B-frag dbuf][2KB edstp][2KB adj] = 20KB (80KB/block,
// 2 blocks/CU). edstp + adj staged ONCE in the prologue; steady state is
// exactly 8 global_load_lds + s_waitcnt vmcnt(8) per tile — no register
// prefetch, no extra load chains. p-gen reads scalars from LDS (broadcast).
// ---------------------------------------------------------------------------
__global__ __launch_bounds__(256) void attn_mfma(
    const short* __restrict__ WhF, const unsigned char* __restrict__ adjbits,
    const float2* __restrict__ esrcp, const u32* __restrict__ edstp,
    float* __restrict__ out) {
  extern __shared__ __align__(16) char smem[];  // 4 waves x 20480 B
  const int t = threadIdx.x;
  const int lane = t & 63;
  const int jq = t >> 6;
  const int col = lane & 15, kgrp = lane >> 4;
  const int h = blockIdx.y;
  const int i0 = blockIdx.x * 32;
  char* wbase = smem + jq * 20480;
  char* dbuf = wbase;          // [2][8192] B-fragments
  char* elds = wbase + 16384;  // 2048 B: edstp[jq*512 ..)
  char* albs = wbase + 18432;  // 2048 B: adj bits [32 rows][64 B]

  const short* tb = WhF + ((size_t)h * 32 + jq * 8) * 4096;
  const int jb = jq * 512;

  const float2 e0 = esrcp[h * NN + i0 + col];
  const float2 e1 = esrcp[h * NN + i0 + 16 + col];
  const float A0 = e0.x, C0 = e0.y, A1 = e1.x, C1 = e1.y;

  bf16x8 ones;
#pragma unroll
  for (int u = 0; u < 8; ++u) ones[u] = (short)0x3F80;

  f32x4 acc[2][4] = {};
  f32x4 accd[2] = {};

  // ---- prologue: stage scalars (once) + tile 0; 12 DMAs total ----
  {
#pragma unroll
    for (int d = 0; d < 2; ++d)
      gl_lds16(edstp + h * NN + jb + d * 256 + lane * 4, elds + d * 1024);
#pragma unroll
    for (int d = 0; d < 2; ++d)
      gl_lds16(adjbits + (size_t)(i0 + d * 16 + (lane >> 2)) * (NN / 8) +
                   jq * 64 + (lane & 3) * 16,
               albs + d * 1024);
#pragma unroll
    for (int s = 0; s < 8; ++s)
      gl_lds16(tb + s * 512 + lane * 8, dbuf + s * 1024);
  }

#pragma unroll
  for (int tt = 0; tt < 8; ++tt) {
    const int cur = tt & 1, nxt = cur ^ 1;

    // ---- issue tile tt+1 (8 DMAs), then wait for tile tt ----
    if (tt < 7) {
      const short* g = tb + (size_t)(tt + 1) * 4096;
      char* sb = dbuf + nxt * 8192;
#pragma unroll
      for (int s = 0; s < 8; ++s)
        gl_lds16(g + s * 512 + lane * 8, sb + s * 1024);
      asm volatile("s_waitcnt vmcnt(8)" ::: "memory");
    } else {
      asm volatile("s_waitcnt vmcnt(0)" ::: "memory");
    }
    __builtin_amdgcn_sched_barrier(0);

    // ---- p-gen from LDS-held scalars ----
    const u32* eu = (const u32*)elds;
    const u64 m0 = *(const u64*)(albs + col * 64 + tt * 8);
    const u64 m1 = *(const u64*)(albs + (16 + col) * 64 + tt * 8);
    bf16x8 af0[2], af1[2];
#pragma unroll
    for (int ks = 0; ks < 2; ++ks) {
      const uint4 q0 = *(const uint4*)&eu[tt * 64 + ks * 32 + kgrp * 8];
      const uint4 q1 = *(const uint4*)&eu[tt * 64 + ks * 32 + kgrp * 8 + 4];
      const u32 mb0 = (u32)(m0 >> ((ks * 4 + kgrp) * 8)) & 0xffu;
      const u32 mb1 = (u32)(m1 >> ((ks * 4 + kgrp) * 8)) & 0xffu;
      const u32 uw[8] = {q0.x, q0.y, q0.z, q0.w, q1.x, q1.y, q1.z, q1.w};
#pragma unroll
      for (int u2 = 0; u2 < 8; ++u2) {
        const float B = __uint_as_float(uw[u2] << 16);
        const float D = __uint_as_float(uw[u2] & 0xffff0000u);
        float p0 = fmaxf(A0 * B, C0 * D);
        float p1 = fmaxf(A1 * B, C1 * D);
        p0 = ((mb0 >> u2) & 1u) ? p0 : 0.f;
        p1 = ((mb1 >> u2) & 1u) ? p1 : 0.f;
        af0[ks][u2] = tob(p0);
        af1[ks][u2] = tob(p1);
      }
    }

    // ---- MFMAs: denominators + 4 od-tiles (B frags from current buffer) ----
    const short* sb = (const short*)(dbuf + cur * 8192);
    __builtin_amdgcn_s_setprio(1);
    accd[0] = __builtin_amdgcn_mfma_f32_16x16x32_bf16(af0[0], ones, accd[0], 0, 0, 0);
    accd[0] = __builtin_amdgcn_mfma_f32_16x16x32_bf16(af0[1], ones, accd[0], 0, 0, 0);
    accd[1] = __builtin_amdgcn_mfma_f32_16x16x32_bf16(af1[0], ones, accd[1], 0, 0, 0);
    accd[1] = __builtin_amdgcn_mfma_f32_16x16x32_bf16(af1[1], ones, accd[1], 0, 0, 0);
#pragma unroll
    for (int nt = 0; nt < 4; ++nt) {
      const bf16x8 b0 = *(const bf16x8*)&sb[(nt * 2 + 0) * 512 + lane * 8];
      const bf16x8 b1 = *(const bf16x8*)&sb[(nt * 2 + 1) * 512 + lane * 8];
      acc[0][nt] = __builtin_amdgcn_mfma_f32_16x16x32_bf16(af0[0], b0, acc[0][nt], 0, 0, 0);
      acc[1][nt] = __builtin_amdgcn_mfma_f32_16x16x32_bf16(af1[0], b0, acc[1][nt], 0, 0, 0);
      acc[0][nt] = __builtin_amdgcn_mfma_f32_16x16x32_bf16(af0[1], b1, acc[0][nt], 0, 0, 0);
      acc[1][nt] = __builtin_amdgcn_mfma_f32_16x16x32_bf16(af1[1], b1, acc[1][nt], 0, 0, 0);
    }
    __builtin_amdgcn_s_setprio(0);
  }

  // ---- all staging done; alias reduce buffer over it ----
  __syncthreads();
  float* red = (float*)smem;  // [4 jq][32 row][66]; den at col 64
  float* rw = red + (size_t)jq * 32 * 66;
#pragma unroll
  for (int mt = 0; mt < 2; ++mt) {
#pragma unroll
    for (int nt = 0; nt < 4; ++nt)
#pragma unroll
      for (int r = 0; r < 4; ++r)
        rw[(mt * 16 + kgrp * 4 + r) * 66 + nt * 16 + col] = acc[mt][nt][r];
    if (col == 0) {
#pragma unroll
      for (int r = 0; r < 4; ++r)
        rw[(mt * 16 + kgrp * 4 + r) * 66 + 64] = accd[mt][r];
    }
  }
  __syncthreads();

  // ---- cross-jq reduce + normalize + store ----
  const int d = t & 63, rl = t >> 6;
#pragma unroll
  for (int rr = 0; rr < 8; ++rr) {
    const int row = rr * 4 + rl;
    float v = 0.f, dd = 0.f;
#pragma unroll
    for (int q = 0; q < 4; ++q) {
      v += red[((size_t)q * 32 + row) * 66 + d];
      dd += red[((size_t)q * 32 + row) * 66 + 64];
    }
    out[(size_t)(i0 + row) * ODIM + h * HD + d] = v / dd;
  }
}

// ---------------------------------------------------------------------------
extern "C" void kernel_launch(void* const* d_in, const int* in_sizes, int n_in,
                              void* d_out, int out_size, void* d_ws,
                              size_t ws_size, hipStream_t stream) {
  const float* x = (const float*)d_in[0];
  const int* adj = (const int*)d_in[1];
  const float* W = (const float*)d_in[2];
  const float* a = (const float*)d_in[3];
  float* out = (float*)d_out;

  char* ws = (char*)d_ws;
  short* WhF = (short*)ws;                                    // 2 MB
  short* Xf = (short*)(ws + (2 << 20));                       // 2 MB
  short* Bf = (short*)(ws + (4 << 20));                       // 512 KB
  unsigned short* bits =
      (unsigned short*)(ws + (4 << 20) + (512 << 10));        // 512 KB
  float2* esrcp = (float2*)(ws + (5 << 20));                  // 128 KB
  u32* edstp = (u32*)(ws + (5 << 20) + (128 << 10));          // 64 KB

  prep<<<1216, 256, 0, stream>>>(x, W, adj, Xf, Bf, bits);
  gemm_fused<<<dim3(32, 8), 256, 0, stream>>>(Xf, Bf, a, WhF, esrcp, edstp);
  attn_mfma<<<dim3(64, 8), 256, 81920, stream>>>(
      WhF, (const unsigned char*)bits, esrcp, edstp, out);
}

// Round 13
// 34.864 us; speedup vs baseline: 1.1733x; 1.0488x over previous
//
#include <hip/hip_runtime.h>
#include <hip/hip_bf16.h>

#define NN 2048
#define KD 512
#define ODIM 512
#define NHEAD 8
#define HD 64
#define NEG 0.2f

typedef float f32x4 __attribute__((ext_vector_type(4)));
typedef short bf16x8 __attribute__((ext_vector_type(8)));
typedef short bf16x4 __attribute__((ext_vector_type(4)));
typedef unsigned int u32x4 __attribute__((ext_vector_type(4)));
typedef unsigned long long u64;
typedef unsigned int u32;

__device__ __forceinline__ short tob(float f) {
  __hip_bfloat16 h = __float2bfloat16(f);
  return *reinterpret_cast<short*>(&h);
}

// async global -> LDS; LDS dest = uniform base + lane*16
__device__ __forceinline__ void gl_lds16(const void* g, void* l) {
  __builtin_amdgcn_global_load_lds(
      (const __attribute__((address_space(1))) u32*)g,
      (__attribute__((address_space(3))) u32*)l, 16, 0, 0);
}

__device__ __forceinline__ u32 to_lds(const void* p) {
  return (u32)(size_t)(const __attribute__((address_space(3))) char*)p;
}

// inline-asm ds_read_b128: opaque to the waitcnt legalizer (no auto drains)
#define DSR(dst, addr, OFFLIT)                      \
  asm volatile("ds_read_b128 %0, %1 offset:" OFFLIT \
               : "=v"(dst)                          \
               : "v"(addr))

// ---------------------------------------------------------------------------
// prep: blocks 0..1023   pack adj -> bitmask
//       blocks 1024..1151 Xf: X (f32) -> bf16 in MFMA-A-fragment order
//       blocks 1152..1215 Bf: W (f32) -> bf16 in MFMA-B-fragment order
// ---------------------------------------------------------------------------
__global__ __launch_bounds__(256) void prep(const float* __restrict__ X,
                                            const float* __restrict__ W,
                                            const int* __restrict__ adj,
                                            short* __restrict__ Xf,
                                            short* __restrict__ Bf,
                                            unsigned short* __restrict__ bits) {
  __shared__ float sbuf[16 * 516];
  const int b = blockIdx.x;
  const int t = threadIdx.x;

  if (b < 1024) {  // ---- adj pack ----
    const int T = b * 256 + t;
    const int row = T >> 7, g = T & 127;
    const int* p = adj + (size_t)row * NN + g * 16;
    u32 m = 0;
#pragma unroll
    for (int q = 0; q < 4; ++q) {
      const int4 v = *(const int4*)&p[q * 4];
      m |= (v.x > 0 ? 1u : 0u) << (q * 4);
      m |= (v.y > 0 ? 2u : 0u) << (q * 4);
      m |= (v.z > 0 ? 4u : 0u) << (q * 4);
      m |= (v.w > 0 ? 8u : 0u) << (q * 4);
    }
    bits[T] = (unsigned short)m;
    return;
  }

  if (b < 1024 + 128) {  // ---- X -> Xf ----
    const int xb = b - 1024;
#pragma unroll
    for (int q = 0; q < 8; ++q) {
      const int flat = q * 256 + t;
      const int row = flat >> 7, c4 = flat & 127;
      const float4 v = *(const float4*)&X[(size_t)(xb * 16 + row) * KD + c4 * 4];
      *(float4*)&sbuf[row * 516 + c4 * 4] = v;
    }
    __syncthreads();
#pragma unroll
    for (int c = 0; c < 4; ++c) {
      const int s = c * 256 + t;
      const int l = s & 63;
      const int col = l & 15, kg = (l >> 4) & 3;
      const int k0 = (s >> 6) * 32 + kg * 8;
      bf16x8 o;
#pragma unroll
      for (int u = 0; u < 8; ++u) o[u] = tob(sbuf[col * 516 + k0 + u]);
      *(bf16x8*)&Xf[((size_t)xb * 1024 + s) * 8] = o;
    }
    return;
  }

  // ---- W -> Bf ----
  const int b2 = b - 1152;
  const int kb = b2 & 7, h = b2 >> 3;
  const int k0 = kb * 64;
#pragma unroll
  for (int q = 0; q < 4; ++q) {
    const int flat = q * 256 + t;
    const int kk = flat >> 4, o4 = (flat & 15) * 4;
    const float4 v = *(const float4*)&W[(size_t)(k0 + kk) * ODIM + h * 64 + o4];
    *(float4*)&sbuf[kk * 68 + o4] = v;
  }
  __syncthreads();
#pragma unroll
  for (int c = 0; c < 2; ++c) {
    const int s = c * 256 + t;
    const int ksl = s >> 8, nt = (s >> 6) & 3, l = s & 63;
    const int col = l & 15, kg = (l >> 4) & 3;
    const int kloc = ksl * 32 + kg * 8;
    const int od = nt * 16 + col;
    bf16x8 o;
#pragma unroll
    for (int u = 0; u < 8; ++u) o[u] = tob(sbuf[(kloc + u) * 68 + od]);
    const size_t off = (((size_t)(h * 4 + nt) * 16 + kb * 2 + ksl) * 64 + l) * 8;
    *(bf16x8*)&Bf[off] = o;
  }
}

// ---------------------------------------------------------------------------
// gemm_fused: grid (64, 8), 256 thr = 4 waves; block = 32 m-rows x head h.
// Waves split k (w&1 = m-tile, w>>1 = k-half), combine partials in LDS;
// waves 0-1 run the epilogue (s-dots, exp tables, fragment-ordered WhF).
// 2 blocks/CU (double the R11 gemm occupancy).
// ---------------------------------------------------------------------------
__global__ __launch_bounds__(256) void gemm_fused(
    const short* __restrict__ Xf, const short* __restrict__ Bf,
    const float* __restrict__ a, short* __restrict__ WhF,
    float2* __restrict__ esrcp, u32* __restrict__ edstp) {
  __shared__ float pbuf[4 * 4 * 64 * 4];  // 16 KB
  const int t = threadIdx.x;
  const int lane = t & 63, w = t >> 6;
  const int col = lane & 15, kgrp = lane >> 4;
  const int bx = blockIdx.x;
  const int h = blockIdx.y;
  const int i0 = bx * 32;

  {
    const int mtg = bx * 2 + (w & 1);  // global 16-row m-tile
    const int kh = w >> 1;             // k-half
    const short* ax = Xf + (size_t)mtg * 8192;
    const short* bxp = Bf + (size_t)h * 32768;

    f32x4 acc1[4] = {};
#pragma unroll
    for (int k2 = 0; k2 < 8; ++k2) {
      const int ks = kh * 8 + k2;
      const bf16x8 af = *(const bf16x8*)&ax[(ks * 64 + lane) * 8];
#pragma unroll
      for (int nt = 0; nt < 4; ++nt) {
        const bf16x8 bf = *(const bf16x8*)&bxp[((nt * 16 + ks) * 64 + lane) * 8];
        acc1[nt] = __builtin_amdgcn_mfma_f32_16x16x32_bf16(af, bf, acc1[nt], 0, 0, 0);
      }
    }
#pragma unroll
    for (int nt = 0; nt < 4; ++nt)
      *(f32x4*)&pbuf[((w * 4 + nt) * 64 + lane) * 4] = acc1[nt];
  }
  __syncthreads();

  if (w < 2) {
    f32x4 acc[4];
#pragma unroll
    for (int nt = 0; nt < 4; ++nt) {
      const f32x4 p0 = *(const f32x4*)&pbuf[((w * 4 + nt) * 64 + lane) * 4];
      const f32x4 p1 = *(const f32x4*)&pbuf[(((w + 2) * 4 + nt) * 64 + lane) * 4];
      acc[nt] = p0 + p1;
    }
    float asv[4], adv[4];
#pragma unroll
    for (int nt = 0; nt < 4; ++nt) {
      asv[nt] = a[nt * 16 + col];
      adv[nt] = a[64 + nt * 16 + col];
    }
    float ps[4], pd[4];
#pragma unroll
    for (int r = 0; r < 4; ++r) {
      float s1 = 0.f, s2 = 0.f;
#pragma unroll
      for (int nt = 0; nt < 4; ++nt) {
        s1 += acc[nt][r] * asv[nt];
        s2 += acc[nt][r] * adv[nt];
      }
      ps[r] = s1;
      pd[r] = s2;
    }
#pragma unroll
    for (int off = 1; off <= 8; off <<= 1) {
#pragma unroll
      for (int r = 0; r < 4; ++r) {
        ps[r] += __shfl_xor(ps[r], off);
        pd[r] += __shfl_xor(pd[r], off);
      }
    }
    // fragment-ordered WhF store: j-tile = bx>>1, within-tile half = bx&1
    {
      const size_t tbase = ((size_t)h * 32 + (bx >> 1)) * 4096;
      const int lp = (w * 2 + (kgrp >> 1)) * 16 + col;
      const int u0 = (kgrp & 1) * 4;
      const int slot_ks = bx & 1;
#pragma unroll
      for (int nt = 0; nt < 4; ++nt) {
        bf16x4 o;
#pragma unroll
        for (int r = 0; r < 4; ++r) o[r] = tob(acc[nt][r]);
        *(bf16x4*)&WhF[tbase + (size_t)(nt * 2 + slot_ks) * 512 + lp * 8 + u0] = o;
      }
    }
    if (col == 0) {
      const int mbase = i0 + w * 16 + kgrp * 4;
#pragma unroll
      for (int r = 0; r < 4; ++r) {
        const int n = mbase + r;
        esrcp[h * NN + n] = make_float2(__expf(ps[r]), __expf(NEG * ps[r]));
        const u32 lo = (u32)(unsigned short)tob(__expf(pd[r]));
        const u32 hi = (u32)(unsigned short)tob(__expf(NEG * pd[r]));
        edstp[h * NN + n] = (hi << 16) | lo;
      }
    }
  }
}

// ---------------------------------------------------------------------------
// attn_mfma: grid (64, 8), 512 thr = 8 waves = 2 m-halves x 4 j-quarters.
// Each jq PAIR shares a 16KB B-frag double-buffer + 2KB edstp (18KB x 4 =
// 72KB -> 2 blocks/CU = 16 waves/CU, 2x prior TLP). Per tile: each wave
// stages 4 of 8 slots (global_load_lds), waits its OWN vmcnt(4), then raw
// s_barrier joins the pair (no compiler vmcnt(0) drain). All loop LDS reads
// are inline-asm ds_read_b128. adj in registers, loaded once.
// ---------------------------------------------------------------------------
__global__ __launch_bounds__(512, 4) void attn_mfma(
    const short* __restrict__ WhF, const unsigned char* __restrict__ adjbits,
    const float2* __restrict__ esrcp, const u32* __restrict__ edstp,
    float* __restrict__ out) {
  extern __shared__ __align__(16) char smem[];  // 4 jq x 18432 B = 73728 B
  const int t = threadIdx.x;
  const int lane = t & 63;
  const int wid = t >> 6;
  const int jq = wid & 3;
  const int mh = wid >> 2;
  const int col = lane & 15, kgrp = lane >> 4;
  const int h = blockIdx.y;
  const int i0 = blockIdx.x * 32;
  const int irow = i0 + mh * 16;

  char* qbase = smem + jq * 18432;
  char* dbuf = qbase;          // [2][8192] B-fragments (shared by the pair)
  char* elds = qbase + 16384;  // 2048 B edstp

  const short* tb = WhF + ((size_t)h * 32 + jq * 8) * 4096;
  const int jb = jq * 512;

  const float2 e0 = esrcp[h * NN + irow + col];
  const float A0 = e0.x, C0 = e0.y;

  // adj words for this wave's 16 rows x 512 j (loaded once, registers)
  u64 aw[8];
  {
    const unsigned char* rb = adjbits + (size_t)(irow + col) * (NN / 8) + jq * 64;
#pragma unroll
    for (int q = 0; q < 4; ++q) {
      const uint4 v = *(const uint4*)(rb + q * 16);
      aw[q * 2] = (u64)v.x | ((u64)v.y << 32);
      aw[q * 2 + 1] = (u64)v.z | ((u64)v.w << 32);
    }
  }

  bf16x8 ones;
#pragma unroll
  for (int u = 0; u < 8; ++u) ones[u] = (short)0x3F80;

  f32x4 acc[4] = {};
  f32x4 accd = {};

  const u32 lread = to_lds(dbuf) + (u32)lane * 16u;
  const u32 eread = to_lds(elds) + (u32)kgrp * 32u;

  // ---- prologue: this wave stages its half of edstp + tile-0 slots ----
  {
    gl_lds16(edstp + h * NN + jb + mh * 256 + lane * 4, elds + mh * 1024);
#pragma unroll
    for (int s = 0; s < 4; ++s) {
      const int slot = mh * 4 + s;
      gl_lds16(tb + slot * 512 + lane * 8, dbuf + slot * 1024);
    }
  }

#pragma unroll
  for (int tt = 0; tt < 8; ++tt) {
    const int cur = tt & 1, nxt = cur ^ 1;

    // ---- issue this wave's 4 slots of tile tt+1, wait own tile-tt loads ----
    if (tt < 7) {
      const short* g = tb + (size_t)(tt + 1) * 4096;
      char* sb = dbuf + nxt * 8192;
#pragma unroll
      for (int s = 0; s < 4; ++s) {
        const int slot = mh * 4 + s;
        gl_lds16(g + slot * 512 + lane * 8, sb + slot * 1024);
      }
      asm volatile("s_waitcnt vmcnt(4)" ::: "memory");
    } else {
      asm volatile("s_waitcnt vmcnt(0)" ::: "memory");
    }
    __builtin_amdgcn_sched_barrier(0);
    __builtin_amdgcn_s_barrier();  // pair-join: partner's slots also landed

    // ---- asm LDS reads: 8 B-frag slots + edstp quads ----
    const u32 abuf = lread + (u32)(cur * 8192);
    bf16x8 b0, b1, b2, b3, b4, b5, b6, b7;
    DSR(b0, abuf, "0");
    DSR(b1, abuf, "1024");
    DSR(b2, abuf, "2048");
    DSR(b3, abuf, "3072");
    DSR(b4, abuf, "4096");
    DSR(b5, abuf, "5120");
    DSR(b6, abuf, "6144");
    DSR(b7, abuf, "7168");
    u32x4 eq[4];
    switch (tt) {  // compile-time offsets (tt unrolled)
      case 0: DSR(eq[0], eread, "0");    DSR(eq[1], eread, "16");   DSR(eq[2], eread, "128");  DSR(eq[3], eread, "144");  break;
      case 1: DSR(eq[0], eread, "256");  DSR(eq[1], eread, "272");  DSR(eq[2], eread, "384");  DSR(eq[3], eread, "400");  break;
      case 2: DSR(eq[0], eread, "512");  DSR(eq[1], eread, "528");  DSR(eq[2], eread, "640");  DSR(eq[3], eread, "656");  break;
      case 3: DSR(eq[0], eread, "768");  DSR(eq[1], eread, "784");  DSR(eq[2], eread, "896");  DSR(eq[3], eread, "912");  break;
      case 4: DSR(eq[0], eread, "1024"); DSR(eq[1], eread, "1040"); DSR(eq[2], eread, "1152"); DSR(eq[3], eread, "1168"); break;
      case 5: DSR(eq[0], eread, "1280"); DSR(eq[1], eread, "1296"); DSR(eq[2], eread, "1408"); DSR(eq[3], eread, "1424"); break;
      case 6: DSR(eq[0], eread, "1536"); DSR(eq[1], eread, "1552"); DSR(eq[2], eread, "1664"); DSR(eq[3], eread, "1680"); break;
      default:DSR(eq[0], eread, "1792"); DSR(eq[1], eread, "1808"); DSR(eq[2], eread, "1920"); DSR(eq[3], eread, "1936"); break;
    }
    asm volatile("s_waitcnt lgkmcnt(0)" ::: "memory");
    __builtin_amdgcn_sched_barrier(0);

    // ---- p-gen (registers only) ----
    bf16x8 af[2];
#pragma unroll
    for (int ks = 0; ks < 2; ++ks) {
      const u32 mb = (u32)(aw[tt] >> ((ks * 4 + kgrp) * 8)) & 0xffu;
      const u32x4 q0 = eq[ks * 2], q1 = eq[ks * 2 + 1];
      const u32 uw[8] = {q0[0], q0[1], q0[2], q0[3], q1[0], q1[1], q1[2], q1[3]};
#pragma unroll
      for (int u2 = 0; u2 < 8; ++u2) {
        const float B = __uint_as_float(uw[u2] << 16);
        const float D = __uint_as_float(uw[u2] & 0xffff0000u);
        float p = fmaxf(A0 * B, C0 * D);
        p = ((mb >> u2) & 1u) ? p : 0.f;
        af[ks][u2] = tob(p);
      }
    }

    // ---- MFMAs: 2 den + 8 od ----
    __builtin_amdgcn_s_setprio(1);
    accd = __builtin_amdgcn_mfma_f32_16x16x32_bf16(af[0], ones, accd, 0, 0, 0);
    accd = __builtin_amdgcn_mfma_f32_16x16x32_bf16(af[1], ones, accd, 0, 0, 0);
    acc[0] = __builtin_amdgcn_mfma_f32_16x16x32_bf16(af[0], b0, acc[0], 0, 0, 0);
    acc[0] = __builtin_amdgcn_mfma_f32_16x16x32_bf16(af[1], b1, acc[0], 0, 0, 0);
    acc[1] = __builtin_amdgcn_mfma_f32_16x16x32_bf16(af[0], b2, acc[1], 0, 0, 0);
    acc[1] = __builtin_amdgcn_mfma_f32_16x16x32_bf16(af[1], b3, acc[1], 0, 0, 0);
    acc[2] = __builtin_amdgcn_mfma_f32_16x16x32_bf16(af[0], b4, acc[2], 0, 0, 0);
    acc[2] = __builtin_amdgcn_mfma_f32_16x16x32_bf16(af[1], b5, acc[2], 0, 0, 0);
    acc[3] = __builtin_amdgcn_mfma_f32_16x16x32_bf16(af[0], b6, acc[3], 0, 0, 0);
    acc[3] = __builtin_amdgcn_mfma_f32_16x16x32_bf16(af[1], b7, acc[3], 0, 0, 0);
    __builtin_amdgcn_s_setprio(0);

    __builtin_amdgcn_s_barrier();  // pair done reading cur -> safe to refill
  }

  // ---- cross-jq reduce (aliases dead staging LDS) ----
  __syncthreads();
  float* red = (float*)smem;  // [2 mh][4 jq][16 row][66]; den at col 64
  float* rw = red + (size_t)((mh * 4 + jq) * 16) * 66;
#pragma unroll
  for (int nt = 0; nt < 4; ++nt)
#pragma unroll
    for (int r = 0; r < 4; ++r)
      rw[(kgrp * 4 + r) * 66 + nt * 16 + col] = acc[nt][r];
  if (col == 0) {
#pragma unroll
    for (int r = 0; r < 4; ++r) rw[(kgrp * 4 + r) * 66 + 64] = accd[r];
  }
  __syncthreads();

  const int d = t & 63, idx = t >> 6;
#pragma unroll
  for (int rr = 0; rr < 4; ++rr) {
    const int row = rr * 8 + idx;
    const int mh2 = row >> 4, r16 = row & 15;
    float v = 0.f, dd = 0.f;
#pragma unroll
    for (int q = 0; q < 4; ++q) {
      const float* rb = red + (size_t)((mh2 * 4 + q) * 16 + r16) * 66;
      v += rb[d];
      dd += rb[64];
    }
    out[(size_t)(i0 + row) * ODIM + h * HD + d] = v / dd;
  }
}

// ---------------------------------------------------------------------------
extern "C" void kernel_launch(void* const* d_in, const int* in_sizes, int n_in,
                              void* d_out, int out_size, void* d_ws,
                              size_t ws_size, hipStream_t stream) {
  const float* x = (const float*)d_in[0];
  const int* adj = (const int*)d_in[1];
  const float* W = (const float*)d_in[2];
  const float* a = (const float*)d_in[3];
  float* out = (float*)d_out;

  char* ws = (char*)d_ws;
  short* WhF = (short*)ws;                                    // 2 MB
  short* Xf = (short*)(ws + (2 << 20));                       // 2 MB
  short* Bf = (short*)(ws + (4 << 20));                       // 512 KB
  unsigned short* bits =
      (unsigned short*)(ws + (4 << 20) + (512 << 10));        // 512 KB
  float2* esrcp = (float2*)(ws + (5 << 20));                  // 128 KB
  u32* edstp = (u32*)(ws + (5 << 20) + (128 << 10));          // 64 KB

  prep<<<1216, 256, 0, stream>>>(x, W, adj, Xf, Bf, bits);
  gemm_fused<<<dim3(64, 8), 256, 0, stream>>>(Xf, Bf, a, WhF, esrcp, edstp);
  attn_mfma<<<dim3(64, 8), 512, 73728, stream>>>(
      WhF, (const unsigned char*)bits, esrcp, edstp, out);
}